// Round 5
// baseline (777.374 us; speedup 1.0000x reference)
//
#include <hip/hip_runtime.h>
#include <hip/hip_bf16.h>

#define DEV __device__ __forceinline__

constexpr int NC = 200000;   // clauses
constexpr int NF = 64;       // features
constexpr int NH = 128;      // hidden
constexpr int NS = 512;      // SEL steps

typedef __attribute__((ext_vector_type(8))) short short8;   // 8 bf16 (4 VGPRs)
typedef __attribute__((ext_vector_type(4))) float f32x4;    // 4 fp32 acc

// ---- workspace layout (float units) ----
constexpr int OF_CFG   = 0;                 // int[16]: [0]=fk(0=f32,1=bf16), [1]=mask bytes (1/2/4)
constexpr int OF_W1    = 16;                // fk=1: 8192 ushort B-frag layout; fk=0: 8192 fp32 transposed
constexpr int OF_B1    = OF_W1 + NF * NH;   // 128 fp32
constexpr int OF_W2K   = OF_B1 + NH;        // 128  (W2 @ key_w)
constexpr int OF_B2K   = OF_W2K + NH;       // 1    (b2 . key_w)
constexpr int OF_MAX   = OF_B2K + 1;        // 1    (flipped-uint global max of logits)
constexpr int OF_ACCE  = OF_MAX + 1;        // 512  sum exp(l-M) over passive
constexpr int OF_ACCP  = OF_ACCE + NS;      // 512  sum logits over passive&proof
constexpr int OF_ACCC  = OF_ACCP + NS;      // 512  count passive&proof
constexpr int OF_EPT   = OF_ACCC + NS;      // 256: float2[c*8+t] = {b1[16t+c], w2k[16t+c]}
constexpr int OF_LOGIT = 16384;             // 200000 fp32 logits

DEV float bf2f(unsigned short u) { return __uint_as_float(((unsigned)u) << 16); }
DEV float loadF(const void* p, int i, int fk) {
    return fk ? bf2f(((const unsigned short*)p)[i]) : ((const float*)p)[i];
}
DEV unsigned flipf(float x) {
    unsigned u = __float_as_uint(x);
    return (u & 0x80000000u) ? ~u : (u | 0x80000000u);
}
DEV float unflipf(unsigned u) {
    unsigned b = (u & 0x80000000u) ? (u ^ 0x80000000u) : ~u;
    return __uint_as_float(b);
}
DEV bool okhalf(unsigned h) { return h == 0u || h == 1u || h == 0x3F80u || h == 0x3C00u; }

// ---------------- K0: dtype probe + weight precompute/permute + zero accumulators ----------------
__global__ void k_probe(const void* features, const void* W1, const void* b1,
                        const void* W2, const void* b2, const void* keyw,
                        const void* sel, float* ws) {
    __shared__ int s_tiny, s_w4, s_w2;
    __shared__ float kw[NH];
    __shared__ float part[256];
    int tx = threadIdx.x;
    if (tx == 0) { s_tiny = 0; s_w4 = 1; s_w2 = 1; }
    __syncthreads();
    {
        const unsigned short* u = (const unsigned short*)features;
        unsigned e = (u[tx] >> 7) & 0xFFu;     // exponent field as-if bf16
        if (e < 100u) atomicAdd(&s_tiny, 1);   // fp32 low-halves: ~39% tiny; bf16 N(0,1): ~0
        const unsigned* w = (const unsigned*)sel;
        unsigned v = w[tx];
        if (!(v == 0u || v == 1u || v == 0x3F800000u)) atomicAnd(&s_w4, 0);
        if (!(okhalf(v & 0xFFFFu) && okhalf(v >> 16))) atomicAnd(&s_w2, 0);
    }
    __syncthreads();
    int fk = (s_tiny >= 8) ? 0 : 1;
    int mw = s_w4 ? 4 : (s_w2 ? 2 : 1);
    if (tx == 0) { ((int*)ws)[0] = fk; ((int*)ws)[1] = mw; }
    if (tx < NH) kw[tx] = loadF(keyw, tx, fk);
    // W1 into the layout the logits kernel wants:
    if (fk) {
        // MFMA B-frag order for 16x16x32 bf16 (HW-verified R3/R4):
        // B[k = ks*32 + (lane>>4)*8 + j][col = 16t + (lane&15)]
        // dst ushort idx = ((t*2+ks)*64 + lane)*8 + j
        const unsigned short* w1u = (const unsigned short*)W1;
        unsigned short* dstp = (unsigned short*)(ws + OF_W1);
        for (int i = tx; i < NF * NH; i += blockDim.x) {
            int k = i >> 7, col = i & 127;
            int t = col >> 4, c = col & 15;
            int ks = k >> 5, kr = k & 31, q = kr >> 3, j = kr & 7;
            dstp[(((t * 2 + ks) * 64) + q * 16 + c) * 8 + j] = w1u[i];
        }
    } else {
        // fp32 transposed: W1t[(jc*NF + f)*4 + c] = W1[f*NH + jc*4 + c]
        for (int i = tx; i < NF * NH; i += blockDim.x) {
            int f = i >> 7, j = i & (NH - 1);
            int jc = j >> 2, c = j & 3;
            ws[OF_W1 + ((jc * NF + f) << 2) + c] = loadF(W1, i, fk);
        }
    }
    if (tx < NH) ws[OF_B1 + tx] = loadF(b1, tx, fk);
    __syncthreads();
    // w2k = W2 @ kw, two threads per row
    {
        int row = tx >> 1, half = tx & 1;
        float s = 0.f;
        for (int k = half * 64; k < half * 64 + 64; k++)
            s += loadF(W2, row * NH + k, fk) * kw[k];
        part[tx] = s;
    }
    __syncthreads();
    if (tx < NH) ws[OF_W2K + tx] = part[2 * tx] + part[2 * tx + 1];
    __syncthreads();
    if (tx < NH) part[tx] = loadF(b2, tx, fk) * kw[tx];
    __syncthreads();
    if (tx == 0) {
        float s = 0.f;
        for (int k = 0; k < NH; k++) s += part[k];
        ws[OF_B2K] = s;
        ((unsigned*)ws)[OF_MAX] = 0u;  // flipped -inf sentinel
    }
    __syncthreads();
    // epilogue table: ept[c*8+t] = {b1[16t+c], w2k[16t+c]}
    if (tx < 128) {
        int c = tx >> 3, t = tx & 7;
        ws[OF_EPT + 2 * tx + 0] = ws[OF_B1 + 16 * t + c];
        ws[OF_EPT + 2 * tx + 1] = ws[OF_W2K + 16 * t + c];
    }
    for (int i = tx; i < 3 * NS; i += blockDim.x) ws[OF_ACCE + i] = 0.f;
}

// ---------------- K1a: MFMA logits (runs iff fk==1) ----------------
__global__ __launch_bounds__(256) void k_logits_mfma(const void* features,
                                                     const float* __restrict__ wsro,
                                                     float* __restrict__ logits,
                                                     unsigned* __restrict__ maxp) {
    __shared__ float4 sW1[1024];   // 16 KB: permuted W1 B-frags, reused by 4 waves x 4 tiles
    int tx = threadIdx.x;
    int fk = ((const int*)wsro)[0];
    if (!fk) return;
    float b2k = wsro[OF_B2K];
    const float4* w1g = (const float4*)(wsro + OF_W1);
    #pragma unroll
    for (int i = 0; i < 4; i++) sW1[tx + i * 256] = w1g[tx + i * 256];
    __syncthreads();
    int wv = tx >> 6, l = tx & 63;
    int m = l & 15, q = l >> 4;
    const short8* bf = (const short8*)sW1;
    const float2* ep = (const float2*)(const void*)(wsro + OF_EPT) + m * 8;
    float mx = -3.0e38f;
    int nbase = blockIdx.x * 256 + wv * 64;
    for (int c = 0; c < 4; c++) {
        int nt = nbase + c * 16;          // NC % 16 == 0: tiles full or fully invalid
        if (nt >= NC) break;
        const unsigned short* fb = (const unsigned short*)features + (size_t)nt * NF;
        short8 a0 = *(const short8*)(fb + m * NF + q * 8);        // A[m][k=q*8+j]
        short8 a1 = *(const short8*)(fb + m * NF + q * 8 + 32);   // A[m][32+k]
        f32x4 acc[8];
        #pragma unroll
        for (int t = 0; t < 8; t++) {
            f32x4 z = {0.f, 0.f, 0.f, 0.f};
            short8 b0 = bf[(t * 2 + 0) * 64 + l];   // ds_read_b128, 2-way alias (free)
            short8 b1f = bf[(t * 2 + 1) * 64 + l];
            z = __builtin_amdgcn_mfma_f32_16x16x32_bf16(a0, b0, z, 0, 0, 0);
            z = __builtin_amdgcn_mfma_f32_16x16x32_bf16(a1, b1f, z, 0, 0, 0);
            acc[t] = z;
        }
        // C layout: col=lane&15 (hidden-in-tile), row=(lane>>4)*4+r (clause)
        float p[4] = {0.f, 0.f, 0.f, 0.f};
        #pragma unroll
        for (int t = 0; t < 8; t++) {
            float2 bw = ep[t];   // {b1, w2k} for col = 16t + m
            #pragma unroll
            for (int r = 0; r < 4; r++)
                p[r] += fmaxf(acc[t][r] + bw.x, 0.f) * bw.y;
        }
        #pragma unroll
        for (int k = 1; k < 16; k <<= 1)
            #pragma unroll
            for (int r = 0; r < 4; r++) p[r] += __shfl_xor(p[r], k, 64);
        if (m == 0) {
            float4 o;
            o.x = p[0] + b2k; o.y = p[1] + b2k; o.z = p[2] + b2k; o.w = p[3] + b2k;
            *(float4*)(logits + nt + q * 4) = o;
            mx = fmaxf(mx, fmaxf(fmaxf(o.x, o.y), fmaxf(o.z, o.w)));
        }
    }
    #pragma unroll
    for (int k = 1; k < 64; k <<= 1) mx = fmaxf(mx, __shfl_xor(mx, k, 64));
    if (l == 0) atomicMax(maxp, flipf(mx));
}

// ---------------- K1b: fp32 fallback logits (runs iff fk==0) ----------------
__global__ __launch_bounds__(256) void k_logits_f32(const void* features,
                                                    const float* __restrict__ wsro,
                                                    float* __restrict__ logits,
                                                    unsigned* __restrict__ maxp) {
    int tx = threadIdx.x;
    int fk = ((const int*)wsro)[0];
    if (fk) return;
    const float* w1t = wsro + OF_W1;
    const float* bias1 = wsro + OF_B1;
    const float* wk = wsro + OF_W2K;
    float b2k = wsro[OF_B2K];
    float acc = -3.0e38f;
    int n = blockIdx.x * 256 + tx;
    if (n < NC) {
        float feat[NF];
        const float4* fp = (const float4*)((const float*)features + (size_t)n * NF);
        #pragma unroll
        for (int qq = 0; qq < 16; qq++) {
            float4 v = fp[qq];
            feat[qq * 4 + 0] = v.x; feat[qq * 4 + 1] = v.y;
            feat[qq * 4 + 2] = v.z; feat[qq * 4 + 3] = v.w;
        }
        acc = b2k;
        for (int jc = 0; jc < NH / 4; jc++) {
            const float4* wp = (const float4*)(w1t + (size_t)jc * (NF * 4)); // uniform s_load
            float4 b = *(const float4*)(bias1 + jc * 4);
            float d0 = b.x, d1 = b.y, d2 = b.z, d3 = b.w;
            #pragma unroll
            for (int f = 0; f < NF; f++) {
                float4 w = wp[f];
                d0 += feat[f] * w.x; d1 += feat[f] * w.y;
                d2 += feat[f] * w.z; d3 += feat[f] * w.w;
            }
            float4 k4 = *(const float4*)(wk + jc * 4);
            acc += fmaxf(d0, 0.f) * k4.x + fmaxf(d1, 0.f) * k4.y
                 + fmaxf(d2, 0.f) * k4.z + fmaxf(d3, 0.f) * k4.w;
        }
        logits[n] = acc;
    }
    float mm = acc;
    #pragma unroll
    for (int k = 1; k < 64; k <<= 1) mm = fmaxf(mm, __shfl_xor(mm, k, 64));
    if ((tx & 63) == 0) atomicMax(maxp, flipf(mm));
}

// ---------------- K2: masked accumulation over sel_mask (prep fused in) ----------------
// NT_N=8 (24 acc VGPRs) + launch_bounds(256,6): ~6 waves/SIMD vs R4's 3. Manual
// next-step prefetch gives 2 loads in flight per wave (~12 outstanding/SIMD).
constexpr int NT_N = 8;             // n per thread (register-resident e/pl/pc)
constexpr int BL_N = 256 * NT_N;    // 2048 n per block
constexpr int SG = 32;              // s per block -> grid (98, 16) = 1568 blocks

struct MV { unsigned v[4]; };       // up to 32 B of mask data per step

template<int MW>
DEV MV mload(const unsigned char* p) {
    MV r;
    if (MW == 1) { uint2 w = *(const uint2*)p; r.v[0] = w.x; r.v[1] = w.y; }
    else if (MW == 2) { uint4 w = *(const uint4*)p; r.v[0] = w.x; r.v[1] = w.y; r.v[2] = w.z; r.v[3] = w.w; }
    else { uint4 w = *(const uint4*)p;  r.v[0] = w.x ? 1u : 0u; r.v[1] = w.y ? 1u : 0u;
           uint4 w2 = *((const uint4*)p + 1); r.v[2] = w.z ? 1u : 0u; r.v[3] = w.w ? 1u : 0u;
           r.v[0] |= 0; (void)w2; r.v[0] = (w.x?1u:0u) | ((w.y?1u:0u)<<8); }
    return r;
}
// (MW==4 path unused when masks are bool; specialized cleanly below instead)

template<int MW>
DEV void mexpand(const MV& w, float (&m)[NT_N]);

template<> DEV void mexpand<1>(const MV& w, float (&m)[NT_N]) {
    #pragma unroll
    for (int q = 0; q < 2; q++)
        #pragma unroll
        for (int b = 0; b < 4; b++)
            m[q * 4 + b] = fminf((float)((w.v[q] >> (8 * b)) & 0xFFu), 1.0f);
}
template<> DEV void mexpand<2>(const MV& w, float (&m)[NT_N]) {
    #pragma unroll
    for (int q = 0; q < 4; q++) {
        m[q * 2 + 0] = (w.v[q] & 0xFFFFu) ? 1.f : 0.f;
        m[q * 2 + 1] = (w.v[q] >> 16) ? 1.f : 0.f;
    }
}
template<> DEV void mexpand<4>(const MV& w, float (&m)[NT_N]) {
    // v[] holds 8 packed "nonzero" bits prepared by mload4
    #pragma unroll
    for (int i = 0; i < 8; i++) m[i] = ((w.v[i >> 2] >> (8 * (i & 3))) & 1u) ? 1.f : 0.f;
}

DEV MV mload4(const unsigned char* p) {  // MW==4: 8 words -> packed nonzero bytes
    uint4 a = *(const uint4*)p, b = *((const uint4*)p + 1);
    MV r;
    r.v[0] = (a.x?1u:0u) | ((a.y?1u:0u)<<8) | ((a.z?1u:0u)<<16) | ((a.w?1u:0u)<<24);
    r.v[1] = (b.x?1u:0u) | ((b.y?1u:0u)<<8) | ((b.z?1u:0u)<<16) | ((b.w?1u:0u)<<24);
    r.v[2] = r.v[3] = 0u;
    return r;
}

template<int MW>
DEV void bloop(const void* sel, int s0, int baddr,
               const float (&e)[NT_N], const float (&pl)[NT_N], const float (&pc)[NT_N],
               float* ws) {
    const unsigned char* p8 = (const unsigned char*)sel + ((size_t)s0 * NC + (size_t)baddr) * MW;
    const size_t stride = (size_t)NC * MW;
    MV cur = (MW == 4) ? mload4(p8) : mload<MW>(p8);
    for (int si = 0; si < SG; si++) {
        // prefetch next step's mask (clamped to a valid address on the last iter)
        const unsigned char* pn = p8 + ((si + 1 < SG) ? stride : 0);
        MV nxt = (MW == 4) ? mload4(pn) : mload<MW>(pn);
        float m[NT_N];
        mexpand<MW>(cur, m);
        float se = 0.f, sp = 0.f, sc = 0.f;
        #pragma unroll
        for (int i = 0; i < NT_N; i++) {
            se += m[i] * e[i]; sp += m[i] * pl[i]; sc += m[i] * pc[i];
        }
        #pragma unroll
        for (int k = 1; k < 64; k <<= 1) {
            se += __shfl_xor(se, k, 64);
            sp += __shfl_xor(sp, k, 64);
            sc += __shfl_xor(sc, k, 64);
        }
        int s = s0 + si;
        if ((threadIdx.x & 63) == 0) {
            atomicAdd(&ws[OF_ACCE + s], se);
            atomicAdd(&ws[OF_ACCP + s], sp);
            atomicAdd(&ws[OF_ACCC + s], sc);
        }
        cur = nxt;
        p8 += stride;
    }
}

__global__ __launch_bounds__(256, 6) void k_phaseB(const void* sel, const void* proof,
                                                   const float* __restrict__ logits,
                                                   float* ws) {
    int tx = threadIdx.x;
    int base = blockIdx.x * BL_N + tx * NT_N;
    int s0 = blockIdx.y * SG;
    bool active = base < NC;                 // NC % 8 == 0: active threads fully valid
    int baddr = active ? base : 0;
    float af = active ? 1.f : 0.f;
    int mw = ((const int*)ws)[1];
    float M = unflipf(((const unsigned*)ws)[OF_MAX]);
    // load logits + proof; build e / pl / pc in registers (prep fused)
    float lg[NT_N], pf[NT_N];
    #pragma unroll
    for (int q = 0; q < 2; q++) {
        float4 v = ((const float4*)(logits + baddr))[q];
        lg[q * 4 + 0] = v.x; lg[q * 4 + 1] = v.y; lg[q * 4 + 2] = v.z; lg[q * 4 + 3] = v.w;
    }
    {
        MV w;
        if (mw == 1)      w = mload<1>((const unsigned char*)proof + (size_t)baddr);
        else if (mw == 2) w = mload<2>((const unsigned char*)proof + (size_t)baddr * 2);
        else              w = mload4((const unsigned char*)proof + (size_t)baddr * 4);
        if (mw == 1)      mexpand<1>(w, pf);
        else if (mw == 2) mexpand<2>(w, pf);
        else              mexpand<4>(w, pf);
    }
    float e[NT_N], pl[NT_N], pc[NT_N];
    #pragma unroll
    for (int i = 0; i < NT_N; i++) {
        e[i]  = af * __expf(lg[i] - M);
        pl[i] = af * pf[i] * lg[i];
        pc[i] = af * pf[i];
    }
    if (mw == 1)      bloop<1>(sel, s0, baddr, e, pl, pc, ws);
    else if (mw == 2) bloop<2>(sel, s0, baddr, e, pl, pc, ws);
    else              bloop<4>(sel, s0, baddr, e, pl, pc, ws);
}

// ---------------- K3: per-step loss + mean, cast to output dtype ----------------
__global__ void k_final(float* ws, void* out) {
    __shared__ float sred[256];
    int tx = threadIdx.x;
    float M = unflipf(((const unsigned*)ws)[OF_MAX]);
    float sum = 0.f;
    for (int s = tx; s < NS; s += 256) {
        float lse = M + logf(ws[OF_ACCE + s]);
        sum += lse - ws[OF_ACCP + s] / ws[OF_ACCC + s];
    }
    sred[tx] = sum;
    __syncthreads();
    for (int k = 128; k > 0; k >>= 1) {
        if (tx < k) sred[tx] += sred[tx + k];
        __syncthreads();
    }
    if (tx == 0) {
        float loss = sred[0] / (float)NS;
        int fk = ((const int*)ws)[0];
        if (fk) ((__hip_bfloat16*)out)[0] = __float2bfloat16(loss);
        else    ((float*)out)[0] = loss;
    }
}

extern "C" void kernel_launch(void* const* d_in, const int* in_sizes, int n_in,
                              void* d_out, int out_size, void* d_ws, size_t ws_size,
                              hipStream_t stream) {
    const void* features = d_in[0];
    const void* W1   = d_in[1];
    const void* b1   = d_in[2];
    const void* W2   = d_in[3];
    const void* b2   = d_in[4];
    const void* keyw = d_in[5];
    const void* sel  = d_in[6];
    const void* proof = d_in[7];
    float* ws = (float*)d_ws;

    k_probe<<<1, 256, 0, stream>>>(features, W1, b1, W2, b2, keyw, sel, ws);
    int nblk = (NC + 255) / 256;   // 782
    k_logits_mfma<<<nblk, 256, 0, stream>>>(features, ws, ws + OF_LOGIT,
                                            (unsigned*)ws + OF_MAX);
    k_logits_f32<<<nblk, 256, 0, stream>>>(features, ws, ws + OF_LOGIT,
                                           (unsigned*)ws + OF_MAX);
    dim3 gB((NC + BL_N - 1) / BL_N, NS / SG);   // (98, 16)
    k_phaseB<<<gB, 256, 0, stream>>>(sel, proof, ws + OF_LOGIT, ws);
    k_final<<<1, 256, 0, stream>>>(ws, d_out);
}

// Round 6
// 724.375 us; speedup vs baseline: 1.0732x; 1.0732x over previous
//
#include <hip/hip_runtime.h>
#include <hip/hip_bf16.h>

#define DEV __device__ __forceinline__

constexpr int NC = 200000;   // clauses
constexpr int NF = 64;       // features
constexpr int NH = 128;      // hidden
constexpr int NS = 512;      // SEL steps

typedef __attribute__((ext_vector_type(8))) short short8;   // 8 bf16 (4 VGPRs)
typedef __attribute__((ext_vector_type(4))) float f32x4;    // 4 fp32 acc

// ---- workspace layout (float units) ----
constexpr int OF_CFG   = 0;                 // int[16]: [0]=fk(0=f32,1=bf16), [1]=mask bytes (1/2/4)
constexpr int OF_W1    = 16;                // fk=1: 8192 ushort B-frag layout; fk=0: 8192 fp32 transposed
constexpr int OF_B1    = OF_W1 + NF * NH;   // 128 fp32
constexpr int OF_W2K   = OF_B1 + NH;        // 128  (W2 @ key_w)
constexpr int OF_B2K   = OF_W2K + NH;       // 1    (b2 . key_w)
constexpr int OF_MAX   = OF_B2K + 1;        // 1    (flipped-uint global max of logits)
constexpr int OF_ACCE  = OF_MAX + 1;        // 512  sum exp(l-M) over passive
constexpr int OF_ACCP  = OF_ACCE + NS;      // 512  sum logits over passive&proof
constexpr int OF_ACCC  = OF_ACCP + NS;      // 512  count passive&proof
constexpr int OF_EPT   = OF_ACCC + NS;      // 256: float2[c*8+t] = {b1[16t+c], w2k[16t+c]}
constexpr int OF_LOGIT = 16384;             // 200000 fp32 logits
constexpr int OF_E     = OF_LOGIT + NC;     // 200000 exp(l-M)
constexpr int OF_PL    = OF_E + NC;         // 200000 proof? l : 0
constexpr int OF_PC    = OF_PL + NC;        // 200000 proof? 1 : 0

DEV float bf2f(unsigned short u) { return __uint_as_float(((unsigned)u) << 16); }
DEV float loadF(const void* p, int i, int fk) {
    return fk ? bf2f(((const unsigned short*)p)[i]) : ((const float*)p)[i];
}
DEV unsigned flipf(float x) {
    unsigned u = __float_as_uint(x);
    return (u & 0x80000000u) ? ~u : (u | 0x80000000u);
}
DEV float unflipf(unsigned u) {
    unsigned b = (u & 0x80000000u) ? (u ^ 0x80000000u) : ~u;
    return __uint_as_float(b);
}
DEV bool okhalf(unsigned h) { return h == 0u || h == 1u || h == 0x3F80u || h == 0x3C00u; }

// ---------------- K0: dtype probe + weight precompute/permute + zero accumulators ----------------
__global__ void k_probe(const void* features, const void* W1, const void* b1,
                        const void* W2, const void* b2, const void* keyw,
                        const void* sel, float* ws) {
    __shared__ int s_tiny, s_w4, s_w2;
    __shared__ float kw[NH];
    __shared__ float part[256];
    int tx = threadIdx.x;
    if (tx == 0) { s_tiny = 0; s_w4 = 1; s_w2 = 1; }
    __syncthreads();
    {
        const unsigned short* u = (const unsigned short*)features;
        unsigned e = (u[tx] >> 7) & 0xFFu;     // exponent field as-if bf16
        if (e < 100u) atomicAdd(&s_tiny, 1);   // fp32 low-halves: ~39% tiny; bf16 N(0,1): ~0
        const unsigned* w = (const unsigned*)sel;
        unsigned v = w[tx];
        if (!(v == 0u || v == 1u || v == 0x3F800000u)) atomicAnd(&s_w4, 0);
        if (!(okhalf(v & 0xFFFFu) && okhalf(v >> 16))) atomicAnd(&s_w2, 0);
    }
    __syncthreads();
    int fk = (s_tiny >= 8) ? 0 : 1;
    int mw = s_w4 ? 4 : (s_w2 ? 2 : 1);
    if (tx == 0) { ((int*)ws)[0] = fk; ((int*)ws)[1] = mw; }
    if (tx < NH) kw[tx] = loadF(keyw, tx, fk);
    // W1 into the layout the logits kernel wants:
    if (fk) {
        // MFMA B-frag order for 16x16x32 bf16 (HW-verified R3/R4):
        // B[k = ks*32 + (lane>>4)*8 + j][col = 16t + (lane&15)]
        // dst ushort idx = ((t*2+ks)*64 + lane)*8 + j
        const unsigned short* w1u = (const unsigned short*)W1;
        unsigned short* dstp = (unsigned short*)(ws + OF_W1);
        for (int i = tx; i < NF * NH; i += blockDim.x) {
            int k = i >> 7, col = i & 127;
            int t = col >> 4, c = col & 15;
            int ks = k >> 5, kr = k & 31, q = kr >> 3, j = kr & 7;
            dstp[(((t * 2 + ks) * 64) + q * 16 + c) * 8 + j] = w1u[i];
        }
    } else {
        // fp32 transposed: W1t[(jc*NF + f)*4 + c] = W1[f*NH + jc*4 + c]
        for (int i = tx; i < NF * NH; i += blockDim.x) {
            int f = i >> 7, j = i & (NH - 1);
            int jc = j >> 2, c = j & 3;
            ws[OF_W1 + ((jc * NF + f) << 2) + c] = loadF(W1, i, fk);
        }
    }
    if (tx < NH) ws[OF_B1 + tx] = loadF(b1, tx, fk);
    __syncthreads();
    // w2k = W2 @ kw, two threads per row
    {
        int row = tx >> 1, half = tx & 1;
        float s = 0.f;
        for (int k = half * 64; k < half * 64 + 64; k++)
            s += loadF(W2, row * NH + k, fk) * kw[k];
        part[tx] = s;
    }
    __syncthreads();
    if (tx < NH) ws[OF_W2K + tx] = part[2 * tx] + part[2 * tx + 1];
    __syncthreads();
    if (tx < NH) part[tx] = loadF(b2, tx, fk) * kw[tx];
    __syncthreads();
    if (tx == 0) {
        float s = 0.f;
        for (int k = 0; k < NH; k++) s += part[k];
        ws[OF_B2K] = s;
        ((unsigned*)ws)[OF_MAX] = 0u;  // flipped -inf sentinel
    }
    __syncthreads();
    // epilogue table: ept[c*8+t] = {b1[16t+c], w2k[16t+c]}
    if (tx < 128) {
        int c = tx >> 3, t = tx & 7;
        ws[OF_EPT + 2 * tx + 0] = ws[OF_B1 + 16 * t + c];
        ws[OF_EPT + 2 * tx + 1] = ws[OF_W2K + 16 * t + c];
    }
    for (int i = tx; i < 3 * NS; i += blockDim.x) ws[OF_ACCE + i] = 0.f;
}

// ---------------- K1a: MFMA logits (runs iff fk==1) ----------------
__global__ __launch_bounds__(256) void k_logits_mfma(const void* features,
                                                     const float* __restrict__ wsro,
                                                     float* __restrict__ logits,
                                                     unsigned* __restrict__ maxp) {
    __shared__ float4 sW1[1024];   // 16 KB: permuted W1 B-frags, reused by 4 waves x 4 tiles
    int tx = threadIdx.x;
    int fk = ((const int*)wsro)[0];
    if (!fk) return;
    float b2k = wsro[OF_B2K];
    const float4* w1g = (const float4*)(wsro + OF_W1);
    #pragma unroll
    for (int i = 0; i < 4; i++) sW1[tx + i * 256] = w1g[tx + i * 256];
    __syncthreads();
    int wv = tx >> 6, l = tx & 63;
    int m = l & 15, q = l >> 4;
    const short8* bf = (const short8*)sW1;
    const float2* ep = (const float2*)(const void*)(wsro + OF_EPT) + m * 8;
    float mx = -3.0e38f;
    int nbase = blockIdx.x * 256 + wv * 64;
    for (int c = 0; c < 4; c++) {
        int nt = nbase + c * 16;          // NC % 16 == 0: tiles full or fully invalid
        if (nt >= NC) break;
        const unsigned short* fb = (const unsigned short*)features + (size_t)nt * NF;
        short8 a0 = *(const short8*)(fb + m * NF + q * 8);        // A[m][k=q*8+j]
        short8 a1 = *(const short8*)(fb + m * NF + q * 8 + 32);   // A[m][32+k]
        f32x4 acc[8];
        #pragma unroll
        for (int t = 0; t < 8; t++) {
            f32x4 z = {0.f, 0.f, 0.f, 0.f};
            short8 b0 = bf[(t * 2 + 0) * 64 + l];   // ds_read_b128, 2-way alias (free)
            short8 b1f = bf[(t * 2 + 1) * 64 + l];
            z = __builtin_amdgcn_mfma_f32_16x16x32_bf16(a0, b0, z, 0, 0, 0);
            z = __builtin_amdgcn_mfma_f32_16x16x32_bf16(a1, b1f, z, 0, 0, 0);
            acc[t] = z;
        }
        // C layout: col=lane&15 (hidden-in-tile), row=(lane>>4)*4+r (clause)
        float p[4] = {0.f, 0.f, 0.f, 0.f};
        #pragma unroll
        for (int t = 0; t < 8; t++) {
            float2 bw = ep[t];   // {b1, w2k} for col = 16t + m
            #pragma unroll
            for (int r = 0; r < 4; r++)
                p[r] += fmaxf(acc[t][r] + bw.x, 0.f) * bw.y;
        }
        #pragma unroll
        for (int k = 1; k < 16; k <<= 1)
            #pragma unroll
            for (int r = 0; r < 4; r++) p[r] += __shfl_xor(p[r], k, 64);
        if (m == 0) {
            float4 o;
            o.x = p[0] + b2k; o.y = p[1] + b2k; o.z = p[2] + b2k; o.w = p[3] + b2k;
            *(float4*)(logits + nt + q * 4) = o;
            mx = fmaxf(mx, fmaxf(fmaxf(o.x, o.y), fmaxf(o.z, o.w)));
        }
    }
    #pragma unroll
    for (int k = 1; k < 64; k <<= 1) mx = fmaxf(mx, __shfl_xor(mx, k, 64));
    if (l == 0) atomicMax(maxp, flipf(mx));
}

// ---------------- K1b: fp32 fallback logits (runs iff fk==0) ----------------
__global__ __launch_bounds__(256) void k_logits_f32(const void* features,
                                                    const float* __restrict__ wsro,
                                                    float* __restrict__ logits,
                                                    unsigned* __restrict__ maxp) {
    int tx = threadIdx.x;
    int fk = ((const int*)wsro)[0];
    if (fk) return;
    const float* w1t = wsro + OF_W1;
    const float* bias1 = wsro + OF_B1;
    const float* wk = wsro + OF_W2K;
    float b2k = wsro[OF_B2K];
    float acc = -3.0e38f;
    int n = blockIdx.x * 256 + tx;
    if (n < NC) {
        float feat[NF];
        const float4* fp = (const float4*)((const float*)features + (size_t)n * NF);
        #pragma unroll
        for (int qq = 0; qq < 16; qq++) {
            float4 v = fp[qq];
            feat[qq * 4 + 0] = v.x; feat[qq * 4 + 1] = v.y;
            feat[qq * 4 + 2] = v.z; feat[qq * 4 + 3] = v.w;
        }
        acc = b2k;
        for (int jc = 0; jc < NH / 4; jc++) {
            const float4* wp = (const float4*)(w1t + (size_t)jc * (NF * 4)); // uniform s_load
            float4 b = *(const float4*)(bias1 + jc * 4);
            float d0 = b.x, d1 = b.y, d2 = b.z, d3 = b.w;
            #pragma unroll
            for (int f = 0; f < NF; f++) {
                float4 w = wp[f];
                d0 += feat[f] * w.x; d1 += feat[f] * w.y;
                d2 += feat[f] * w.z; d3 += feat[f] * w.w;
            }
            float4 k4 = *(const float4*)(wk + jc * 4);
            acc += fmaxf(d0, 0.f) * k4.x + fmaxf(d1, 0.f) * k4.y
                 + fmaxf(d2, 0.f) * k4.z + fmaxf(d3, 0.f) * k4.w;
        }
        logits[n] = acc;
    }
    float mm = acc;
    #pragma unroll
    for (int k = 1; k < 64; k <<= 1) mm = fmaxf(mm, __shfl_xor(mm, k, 64));
    if ((tx & 63) == 0) atomicMax(maxp, flipf(mm));
}

// ---------------- K2: e = exp(l - M), proof-gated logits / counts (R2-measured) ----------------
__global__ void k_prep(const void* proof, float* ws) {
    int n = blockIdx.x * 256 + threadIdx.x;
    if (n >= NC) return;
    int mw = ((const int*)ws)[1];
    float M = unflipf(((const unsigned*)ws)[OF_MAX]);
    float l = ws[OF_LOGIT + n];
    ws[OF_E + n] = __expf(l - M);
    bool pf;
    if (mw == 1)      pf = ((const unsigned char*)proof)[n] != 0;
    else if (mw == 2) pf = ((const unsigned short*)proof)[n] != 0;
    else              pf = ((const unsigned*)proof)[n] != 0;
    ws[OF_PL + n] = pf ? l : 0.f;
    ws[OF_PC + n] = pf ? 1.f : 0.f;
}

// ---------------- K3: phaseB v2 — one SEL step per thread ----------------
// Thread t of block (x,y) owns step s = y*256+t and clauses [x*256, x*256+256).
// Private se/sp/sc accumulators: NO shuffle trees, 3 atomics per thread total.
// e/pl/pc addresses are wave-uniform -> scalar loads on the free SMEM pipe.
constexpr int CHUNK = 256;

template<int MW>
DEV void mexp16(const unsigned char* p, float (&m)[16]) {
    if (MW == 1) {
        uint4 w = *(const uint4*)p;
        unsigned v[4] = {w.x, w.y, w.z, w.w};
        #pragma unroll
        for (int q = 0; q < 4; q++)
            #pragma unroll
            for (int b = 0; b < 4; b++)
                m[q * 4 + b] = fminf((float)((v[q] >> (8 * b)) & 0xFFu), 1.0f);
    } else if (MW == 2) {
        #pragma unroll
        for (int h = 0; h < 2; h++) {
            uint4 w = ((const uint4*)p)[h];
            unsigned v[4] = {w.x, w.y, w.z, w.w};
            #pragma unroll
            for (int q = 0; q < 4; q++) {
                m[h * 8 + q * 2 + 0] = (v[q] & 0xFFFFu) ? 1.f : 0.f;
                m[h * 8 + q * 2 + 1] = (v[q] >> 16) ? 1.f : 0.f;
            }
        }
    } else {
        #pragma unroll
        for (int h = 0; h < 4; h++) {
            uint4 w = ((const uint4*)p)[h];
            m[h * 4 + 0] = w.x ? 1.f : 0.f; m[h * 4 + 1] = w.y ? 1.f : 0.f;
            m[h * 4 + 2] = w.z ? 1.f : 0.f; m[h * 4 + 3] = w.w ? 1.f : 0.f;
        }
    }
}

template<int MW>
DEV void bloop2(const unsigned char* mp, int cbase,
                const float* __restrict__ e, const float* __restrict__ pl,
                const float* __restrict__ pc,
                float& se, float& sp, float& sc) {
    for (int c = 0; c < CHUNK; c += 16) {
        int cc = cbase + c;            // uniform
        if (cc >= NC) break;           // uniform branch (NC % 16 == 0)
        float m[16];
        mexp16<MW>(mp + (size_t)c * MW, m);
        #pragma unroll
        for (int q = 0; q < 4; q++) {
            float4 ev = ((const float4*)(e + cc))[q];    // uniform -> s_load
            float4 pv = ((const float4*)(pl + cc))[q];
            float4 cv = ((const float4*)(pc + cc))[q];
            se += m[q*4+0]*ev.x + m[q*4+1]*ev.y + m[q*4+2]*ev.z + m[q*4+3]*ev.w;
            sp += m[q*4+0]*pv.x + m[q*4+1]*pv.y + m[q*4+2]*pv.z + m[q*4+3]*pv.w;
            sc += m[q*4+0]*cv.x + m[q*4+1]*cv.y + m[q*4+2]*cv.z + m[q*4+3]*cv.w;
        }
    }
}

__global__ __launch_bounds__(256) void k_phaseB(const void* sel, float* ws) {
    int s = blockIdx.y * 256 + threadIdx.x;   // this thread's SEL step
    int cbase = blockIdx.x * CHUNK;           // uniform clause base
    int mw = ((const int*)ws)[1];
    const float* e  = ws + OF_E;
    const float* pl = ws + OF_PL;
    const float* pc = ws + OF_PC;
    float se = 0.f, sp = 0.f, sc = 0.f;
    if (mw == 1) {
        const unsigned char* mp = (const unsigned char*)sel + (size_t)s * NC + cbase;
        bloop2<1>(mp, cbase, e, pl, pc, se, sp, sc);
    } else if (mw == 2) {
        const unsigned char* mp = (const unsigned char*)sel + ((size_t)s * NC + cbase) * 2;
        bloop2<2>(mp, cbase, e, pl, pc, se, sp, sc);
    } else {
        const unsigned char* mp = (const unsigned char*)sel + ((size_t)s * NC + cbase) * 4;
        bloop2<4>(mp, cbase, e, pl, pc, se, sp, sc);
    }
    atomicAdd(&ws[OF_ACCE + s], se);
    atomicAdd(&ws[OF_ACCP + s], sp);
    atomicAdd(&ws[OF_ACCC + s], sc);
}

// ---------------- K4: per-step loss + mean, cast to output dtype ----------------
__global__ void k_final(float* ws, void* out) {
    __shared__ float sred[256];
    int tx = threadIdx.x;
    float M = unflipf(((const unsigned*)ws)[OF_MAX]);
    float sum = 0.f;
    for (int s = tx; s < NS; s += 256) {
        float lse = M + logf(ws[OF_ACCE + s]);
        sum += lse - ws[OF_ACCP + s] / ws[OF_ACCC + s];
    }
    sred[tx] = sum;
    __syncthreads();
    for (int k = 128; k > 0; k >>= 1) {
        if (tx < k) sred[tx] += sred[tx + k];
        __syncthreads();
    }
    if (tx == 0) {
        float loss = sred[0] / (float)NS;
        int fk = ((const int*)ws)[0];
        if (fk) ((__hip_bfloat16*)out)[0] = __float2bfloat16(loss);
        else    ((float*)out)[0] = loss;
    }
}

extern "C" void kernel_launch(void* const* d_in, const int* in_sizes, int n_in,
                              void* d_out, int out_size, void* d_ws, size_t ws_size,
                              hipStream_t stream) {
    const void* features = d_in[0];
    const void* W1   = d_in[1];
    const void* b1   = d_in[2];
    const void* W2   = d_in[3];
    const void* b2   = d_in[4];
    const void* keyw = d_in[5];
    const void* sel  = d_in[6];
    const void* proof = d_in[7];
    float* ws = (float*)d_ws;

    k_probe<<<1, 256, 0, stream>>>(features, W1, b1, W2, b2, keyw, sel, ws);
    int nblk = (NC + 255) / 256;   // 782
    k_logits_mfma<<<nblk, 256, 0, stream>>>(features, ws, ws + OF_LOGIT,
                                            (unsigned*)ws + OF_MAX);
    k_logits_f32<<<nblk, 256, 0, stream>>>(features, ws, ws + OF_LOGIT,
                                           (unsigned*)ws + OF_MAX);
    k_prep<<<nblk, 256, 0, stream>>>(proof, ws);
    dim3 gB((NC + CHUNK - 1) / CHUNK, NS / 256);   // (782, 2)
    k_phaseB<<<gB, 256, 0, stream>>>(sel, ws);
    k_final<<<1, 256, 0, stream>>>(ws, d_out);
}